// Round 1
// baseline (149239.978 us; speedup 1.0000x reference)
//
#include <hip/hip_runtime.h>
#include <hip/hip_bf16.h>

// BidRnn: B=128, T=1024, H=512. Bidirectional GRU + scheduled-sampling predictor.
// Round 1: correctness-first, no inter-WG sync. One workgroup per (batch, dir):
// 256 WGs x 256 threads. Weights streamed from L2 each step (port-bound ~14-16ms).
// Runtime probes detect mask encoding (u8 / bf16 / 4-byte) and float dtype
// (bf16 vs fp32) so we are robust to harness dtype conventions.

#define T_STEPS 1024
#define H_DIM   512

__device__ __forceinline__ float bf2f(unsigned int u){
  union { unsigned int i; float f; } v; v.i = u << 16; return v.f;
}
__device__ __forceinline__ float ldw(const float* p){ return *p; }
__device__ __forceinline__ float ldw(const __hip_bfloat16* p){
  unsigned short s = *(const unsigned short*)p; return bf2f((unsigned int)s);
}
// 8 consecutive elements -> fp32
__device__ __forceinline__ void load8(const float* p, float* o){
  const float4 a = ((const float4*)p)[0];
  const float4 b = ((const float4*)p)[1];
  o[0]=a.x;o[1]=a.y;o[2]=a.z;o[3]=a.w;o[4]=b.x;o[5]=b.y;o[6]=b.z;o[7]=b.w;
}
__device__ __forceinline__ void load8(const __hip_bfloat16* p, float* o){
  const uint4 u = *(const uint4*)p;   // 8 bf16 = 16B
  o[0]=bf2f(u.x & 0xFFFFu); o[1]=bf2f(u.x >> 16);
  o[2]=bf2f(u.y & 0xFFFFu); o[3]=bf2f(u.y >> 16);
  o[4]=bf2f(u.z & 0xFFFFu); o[5]=bf2f(u.z >> 16);
  o[6]=bf2f(u.w & 0xFFFFu); o[7]=bf2f(u.w >> 16);
}
__device__ __forceinline__ void stw(float* p, float v){ *p = v; }
__device__ __forceinline__ void stw(__hip_bfloat16* p, float v){ *p = __float2bfloat16(v); }

// ---------------------------------------------------------------------------
// Probe: classify mask encoding and float dtype. Writes codes[0]=mask stride
// (1=u8, 2=bf16 halves, 4=word nonzero covers i32 AND f32), codes[1]=0 bf16 /1 fp32.
// Scans only the first 131072 bytes of mask (valid for every candidate dtype)
// and the first 3072 bytes of wf_ih (1536 elems, |w|<=0.045 so bf16 halves
// always have exponent field < 124; fp32 low halves are random mantissa bits).
// ---------------------------------------------------------------------------
__global__ void probe_kernel(const unsigned int* __restrict__ mw,
                             const unsigned int* __restrict__ ww,
                             int* __restrict__ codes){
  __shared__ unsigned int fl[5];
  if(threadIdx.x < 5) fl[threadIdx.x] = 0u;
  __syncthreads();
  unsigned int l0=0,l1=0,l2=0,l3=0,l4=0;
  for(int i=threadIdx.x; i<32768; i+=256){
    const unsigned int w = mw[i];
    #pragma unroll
    for(int bb=0;bb<4;bb++){
      const unsigned int by = (w >> (8*bb)) & 0xFFu;
      if(by > 1u) l0 = 1u;                 // u8 violation
      if(bb!=0 && by==1u) l1 = 1u;         // u8 evidence (odd-offset byte == 1)
    }
    const unsigned int hlo = w & 0xFFFFu, hhi = w >> 16;
    if(!(hlo==0u || hlo==0x3F80u) || !(hhi==0u || hhi==0x3F80u)) l2 = 1u; // bf16 viol
    if(hlo == 0x3F80u) l3 = 1u;            // bf16 evidence: EVEN-index half==1.0
                                           // (fp32 1.0f has lo half 0x0000)
  }
  for(int i=threadIdx.x; i<768; i+=256){
    const unsigned int w = ww[i];
    const unsigned int hlo = w & 0xFFFFu;
    if(hlo != 0u && ((hlo>>7)&0xFFu) >= 128u) l4 = 1u;  // fp32 evidence
  }
  if(l0) atomicOr(&fl[0],1u);
  if(l1) atomicOr(&fl[1],1u);
  if(l2) atomicOr(&fl[2],1u);
  if(l3) atomicOr(&fl[3],1u);
  if(l4) atomicOr(&fl[4],1u);
  __syncthreads();
  if(threadIdx.x==0){
    int mcode;
    if(!fl[0] && fl[1])      mcode = 1;   // byte mask
    else if(!fl[2] && fl[3]) mcode = 2;   // bf16 mask
    else                     mcode = 4;   // 4-byte mask (i32 or f32: word != 0)
    codes[0] = mcode;
    codes[1] = fl[4] ? 1 : 0;
  }
}

// ---------------------------------------------------------------------------
// Main body. One WG = one (batch b, direction dir). 4 waves:
//  wave0 -> predictor rows p_w1[0..512), waves1-3 -> w_hh rows [0..1536).
// Each row dot: 64 lanes x 8 contiguous elems (coalesced 1KB load) against
// h held in per-lane registers (hreg[q] = h[8*lane+q]); butterfly reduce.
// ---------------------------------------------------------------------------
template<typename WT, typename OT>
__device__ void body(const void* xv_, const void* mk_,
                     const void* wih_, const void* whh_,
                     const void* bihv_, const void* bhhv_,
                     const void* pw1_, const void* pb1v_,
                     const void* pw2v_, const void* pb2_,
                     int mcode, int dir, int b, OT* __restrict__ out,
                     float* S, float* h_s, float* wih, float* bih, float* bhh,
                     float* pb1, float* pw2, float* red, float* xsh)
{
  const int tid  = threadIdx.x;
  const int lane = tid & 63;
  const int wid  = tid >> 6;

  const WT* x    = (const WT*)xv_;
  const unsigned char* mk = (const unsigned char*)mk_;
  const WT* w_ih = (const WT*)wih_;
  const WT* w_hh = (const WT*)whh_;
  const WT* b_ih = (const WT*)bihv_;
  const WT* b_hh = (const WT*)bhhv_;
  const WT* p_w1 = (const WT*)pw1_;
  const WT* p_b1 = (const WT*)pb1v_;
  const WT* p_w2 = (const WT*)pw2v_;
  const WT* p_b2 = (const WT*)pb2_;

  // stage small constants in LDS (fp32)
  for(int i=tid;i<1536;i+=256){ wih[i]=ldw(w_ih+i); bih[i]=ldw(b_ih+i); bhh[i]=ldw(b_hh+i); }
  for(int i=tid;i<512;i+=256){ pb1[i]=ldw(p_b1+i); pw2[i]=ldw(p_w2+i); h_s[i]=0.f; }
  const float pb2v = ldw(p_b2);
  __syncthreads();

  float hreg[8];
  #pragma unroll
  for(int q=0;q<8;q++) hreg[q] = 0.f;     // h0 = 0

  const WT* bp = (wid==0) ? p_w1 : (w_hh + (size_t)(wid-1)*512*H_DIM);
  float* Sb = S + wid*512;                // S[0..512)=p_w1 sums, S[512..2048)=w_hh sums
  const int j1 = tid, j2 = tid + 256;

  for(int t=0;t<T_STEPS;t++){
    const int ts = dir ? (T_STEPS-1-t) : t;

    // prefetch this step's x/mask (latency hidden behind the row loop)
    float xfv = 0.f; bool mfl = false;
    if(tid==0){
      const size_t idx = (size_t)b*T_STEPS + ts;
      if(mcode==1)      mfl = mk[idx] != 0;
      else if(mcode==2) mfl = ((const unsigned short*)mk)[idx] != 0;
      else              mfl = ((const unsigned int*)mk)[idx]  != 0;
      xfv = ldw(x+idx);
    }

    // 512 rows per wave: dot(row, h_{t-1})
    for(int r=0;r<512;r+=2){
      float a[8], c[8];
      load8(bp + (size_t)r*H_DIM     + lane*8, a);
      load8(bp + (size_t)(r+1)*H_DIM + lane*8, c);
      float s0=0.f, s1=0.f;
      #pragma unroll
      for(int q=0;q<8;q++){ s0=fmaf(a[q],hreg[q],s0); s1=fmaf(c[q],hreg[q],s1); }
      #pragma unroll
      for(int off=32;off;off>>=1){ s0 += __shfl_xor(s0,off); s1 += __shfl_xor(s1,off); }
      if(lane==0){ Sb[r]=s0; Sb[r+1]=s1; }
    }
    __syncthreads();                       // A: S complete

    // predictor scalar: tanh( relu(S_q + pb1) . pw2 + pb2 )
    {
      float u1 = S[j1] + pb1[j1]; u1 = u1>0.f?u1:0.f;
      float u2 = S[j2] + pb1[j2]; u2 = u2>0.f?u2:0.f;
      float v = u1*pw2[j1] + u2*pw2[j2];
      #pragma unroll
      for(int off=32;off;off>>=1) v += __shfl_down(v,off,64);
      if(lane==0) red[wid]=v;
    }
    __syncthreads();                       // B: red complete
    if(tid==0){
      const float s = tanhf(red[0]+red[1]+red[2]+red[3] + pb2v);
      xsh[0] = mfl ? s : xfv;
    }
    __syncthreads();                       // C: x_in broadcast
    const float xin = xsh[0];

    // GRU gates for this thread's two h indices
    float hn[2];
    #pragma unroll
    for(int e=0;e<2;e++){
      const int j = e ? j2 : j1;
      const float gr = S[512+j]  + bhh[j];
      const float gz = S[1024+j] + bhh[j+512];
      const float gn = S[1536+j] + bhh[j+1024];
      const float ir = fmaf(xin, wih[j],      bih[j]);
      const float iz = fmaf(xin, wih[j+512],  bih[j+512]);
      const float nn = fmaf(xin, wih[j+1024], bih[j+1024]);
      const float rg = 1.f/(1.f+__expf(-(ir+gr)));
      const float zg = 1.f/(1.f+__expf(-(iz+gz)));
      const float ng = tanhf(fmaf(rg, gn, nn));
      hn[e] = (1.f-zg)*ng + zg*h_s[j];
    }
    __syncthreads();                       // D: all reads of old h_s / S done
    h_s[j1]=hn[0]; h_s[j2]=hn[1];
    {
      OT* op = out + ((size_t)b*T_STEPS + ts)*(2*H_DIM) + (size_t)dir*H_DIM;
      stw(op+j1, hn[0]); stw(op+j2, hn[1]);
    }
    __syncthreads();                       // E: h_s updated
    #pragma unroll
    for(int q=0;q<8;q++) hreg[q] = h_s[lane*8+q];
  }
}

__global__ __launch_bounds__(256)
void rnn_kernel(const void* i0,const void* i1,const void* i2,const void* i3,
                const void* i4,const void* i5,const void* i6,const void* i7,
                const void* i8,const void* i9,const void* i10,const void* i11,
                const void* i12,const void* i13,const int* codes, void* out)
{
  __shared__ float S[2048];
  __shared__ float h_s[512];
  __shared__ float wih[1536], bih[1536], bhh[1536];
  __shared__ float pb1[512], pw2[512];
  __shared__ float red[4];
  __shared__ float xsh[1];

  const int wg  = (int)blockIdx.x;
  const int dir = wg >> 7;
  const int b   = wg & 127;
  const void* w_ih = dir ? i6 : i2;
  const void* w_hh = dir ? i7 : i3;
  const void* b_ih = dir ? i8 : i4;
  const void* b_hh = dir ? i9 : i5;
  const int mcode = codes[0];

  if(codes[1]==0)
    body<__hip_bfloat16,__hip_bfloat16>(i0,i1,w_ih,w_hh,b_ih,b_hh,i10,i11,i12,i13,
        mcode,dir,b,(__hip_bfloat16*)out,S,h_s,wih,bih,bhh,pb1,pw2,red,xsh);
  else
    body<float,float>(i0,i1,w_ih,w_hh,b_ih,b_hh,i10,i11,i12,i13,
        mcode,dir,b,(float*)out,S,h_s,wih,bih,bhh,pb1,pw2,red,xsh);
}

extern "C" void kernel_launch(void* const* d_in, const int* in_sizes, int n_in,
                              void* d_out, int out_size, void* d_ws, size_t ws_size,
                              hipStream_t stream)
{
  (void)in_sizes; (void)n_in; (void)out_size; (void)ws_size;
  int* codes = (int*)d_ws;
  probe_kernel<<<1, 256, 0, stream>>>((const unsigned int*)d_in[1],
                                      (const unsigned int*)d_in[2], codes);
  rnn_kernel<<<256, 256, 0, stream>>>(d_in[0],d_in[1],d_in[2],d_in[3],d_in[4],
                                      d_in[5],d_in[6],d_in[7],d_in[8],d_in[9],
                                      d_in[10],d_in[11],d_in[12],d_in[13],
                                      codes, d_out);
}